// Round 1
// baseline (1324.165 us; speedup 1.0000x reference)
//
#include <hip/hip_runtime.h>
#include <math.h>

#define L_SEQ 1024
#define HDIM  1024
#define NHEAD 16
#define HD    64
#define BATCH 4

// ---------------------------------------------------------------------------
// GEMM: C[M,N] = A[M,K=1024] * W[K=1024,N], fp32, 64x64 tile, BK=16,
// 256 threads, 4x4 microtile per thread.
// mode 0: head-scatter epilogue. Column tile blockIdx.x == global head tile.
//         cols [0,1024) -> dstK, cols [1024,2048) -> dstV, layout [B,NH,L,HD].
// mode 1: plain row-major into dstK [4096,1024].
// ---------------------------------------------------------------------------
__global__ __launch_bounds__(256, 2) void gemm_k1024(
    const float* __restrict__ A, const float* __restrict__ W, int N,
    float* __restrict__ dstK, float* __restrict__ dstV, int mode)
{
    __shared__ __align__(16) float As[16][68];  // [k][row] (transposed)
    __shared__ __align__(16) float Bs[16][68];  // [k][col]
    const int t  = threadIdx.x;
    const int tx = t & 15, ty = t >> 4;
    const int rowBase = blockIdx.y * 64;
    const int colBase = blockIdx.x * 64;

    const int ar = t >> 2;        // 0..63 : A tile row
    const int ak = (t & 3) * 4;   // 0,4,8,12 : A tile k offset
    const int bk = t >> 4;        // 0..15 : B tile k row
    const int bc = (t & 15) * 4;  // col offset within tile

    const float* Aptr = A + (size_t)(rowBase + ar) * 1024 + ak;
    const float* Wptr = W + (size_t)bk * N + colBase + bc;

    float acc[4][4];
#pragma unroll
    for (int i = 0; i < 4; i++)
#pragma unroll
        for (int j = 0; j < 4; j++) acc[i][j] = 0.f;

    for (int kt = 0; kt < 64; ++kt) {
        float4 a = *(const float4*)(Aptr + kt * 16);
        As[ak + 0][ar] = a.x; As[ak + 1][ar] = a.y;
        As[ak + 2][ar] = a.z; As[ak + 3][ar] = a.w;
        float4 b = *(const float4*)(Wptr + (size_t)kt * 16 * N);
        *(float4*)&Bs[bk][bc] = b;
        __syncthreads();
#pragma unroll
        for (int kk = 0; kk < 16; ++kk) {
            float4 av = *(const float4*)&As[kk][ty * 4];
            float4 bv = *(const float4*)&Bs[kk][tx * 4];
            float aa[4] = {av.x, av.y, av.z, av.w};
            float bb[4] = {bv.x, bv.y, bv.z, bv.w};
#pragma unroll
            for (int i = 0; i < 4; i++)
#pragma unroll
                for (int j = 0; j < 4; j++)
                    acc[i][j] = fmaf(aa[i], bb[j], acc[i][j]);
        }
        __syncthreads();
    }

    if (mode == 1) {
#pragma unroll
        for (int i = 0; i < 4; i++) {
            int gr = rowBase + ty * 4 + i;
            float4 v = {acc[i][0], acc[i][1], acc[i][2], acc[i][3]};
            *(float4*)&dstK[(size_t)gr * 1024 + colBase + tx * 4] = v;
        }
    } else {
        int ht = blockIdx.x;  // 64-col tile == exactly one head
        float* dst = dstK;
        int head = ht;
        if (ht >= NHEAD) { dst = dstV; head = ht - NHEAD; }
#pragma unroll
        for (int i = 0; i < 4; i++) {
            int gr = rowBase + ty * 4 + i;
            int b = gr >> 10, l = gr & 1023;
            float4 v = {acc[i][0], acc[i][1], acc[i][2], acc[i][3]};
            *(float4*)&dst[((size_t)(b * NHEAD + head) * L_SEQ + l) * HD + tx * 4] = v;
        }
    }
}

// ---------------------------------------------------------------------------
// Flash-style dual-branch attention. Block = (q-tile of 64 rows, head, batch).
// 256 threads, 4x4 microtile over the 64x64 S / O tiles.
// Branch 0 = short (with decay bias), branch 1 = long. Mix with sigmoid(mw).
// Output written token-major [B, L, H] for the final GEMM.
// ---------------------------------------------------------------------------
__global__ __launch_bounds__(256, 2) void attn_kernel(
    const float* __restrict__ Q, const float* __restrict__ Ks,
    const float* __restrict__ Vs_, const float* __restrict__ Kl,
    const float* __restrict__ Vl, const float* __restrict__ mixw,
    const float* __restrict__ decayf, float* __restrict__ out)
{
    __shared__ __align__(16) float Qs[64][68];   // [d][r], pre-scaled by 1/8
    __shared__ __align__(16) float KP[64][68];   // K as [d][c]; later P as [c][r]
    __shared__ __align__(16) float Vsh[64][68];  // [c][d]
    const int t  = threadIdx.x;
    const int tx = t & 15, ty = t >> 4;
    const int qt = blockIdx.x, h = blockIdx.y, b = blockIdx.z;
    const size_t bh = (size_t)(b * NHEAD + h) * L_SEQ * HD;

    // stage Q tile (transposed, scaled by 1/sqrt(hd)=0.125)
#pragma unroll
    for (int i = 0; i < 4; i++) {
        int u = i * 256 + t;
        int r = u >> 4, d4 = (u & 15) * 4;
        float4 v = *(const float4*)&Q[bh + (size_t)(qt * 64 + r) * HD + d4];
        Qs[d4 + 0][r] = v.x * 0.125f;
        Qs[d4 + 1][r] = v.y * 0.125f;
        Qs[d4 + 2][r] = v.z * 0.125f;
        Qs[d4 + 3][r] = v.w * 0.125f;
    }
    const float lam   = 1.0f - decayf[0];
    const float alpha = 1.0f / (1.0f + __expf(-mixw[0]));

    float outS[4][4];
    float acc[4][4];

    for (int branch = 0; branch < 2; ++branch) {
        const float* K = branch ? Kl : Ks;
        const float* V = branch ? Vl : Vs_;
        float m[4], lsum[4];
#pragma unroll
        for (int i = 0; i < 4; i++) { m[i] = -INFINITY; lsum[i] = 0.f; }
#pragma unroll
        for (int i = 0; i < 4; i++)
#pragma unroll
            for (int j = 0; j < 4; j++) acc[i][j] = 0.f;

        for (int kt = 0; kt < 16; ++kt) {
            __syncthreads();  // protect KP/Vsh (and Qs on first iter) readers/writers
#pragma unroll
            for (int i = 0; i < 4; i++) {
                int u = i * 256 + t;
                int r = u >> 4, d4 = (u & 15) * 4;
                float4 kv = *(const float4*)&K[bh + (size_t)(kt * 64 + r) * HD + d4];
                KP[d4 + 0][r] = kv.x; KP[d4 + 1][r] = kv.y;
                KP[d4 + 2][r] = kv.z; KP[d4 + 3][r] = kv.w;
                float4 vv = *(const float4*)&V[bh + (size_t)(kt * 64 + r) * HD + d4];
                *(float4*)&Vsh[r][d4] = vv;
            }
            __syncthreads();

            // S tile: s[i][j] = sum_d Qs[d][4ty+i] * KP[d][4tx+j]
            float s[4][4];
#pragma unroll
            for (int i = 0; i < 4; i++)
#pragma unroll
                for (int j = 0; j < 4; j++) s[i][j] = 0.f;
            for (int d = 0; d < 64; ++d) {
                float4 q4 = *(const float4*)&Qs[d][ty * 4];
                float4 k4 = *(const float4*)&KP[d][tx * 4];
                float qa[4] = {q4.x, q4.y, q4.z, q4.w};
                float kb[4] = {k4.x, k4.y, k4.z, k4.w};
#pragma unroll
                for (int i = 0; i < 4; i++)
#pragma unroll
                    for (int j = 0; j < 4; j++)
                        s[i][j] = fmaf(qa[i], kb[j], s[i][j]);
            }
            if (branch == 0) {
#pragma unroll
                for (int i = 0; i < 4; i++) {
                    int qi = qt * 64 + ty * 4 + i;
#pragma unroll
                    for (int j = 0; j < 4; j++) {
                        int ki = kt * 64 + tx * 4 + j;
                        s[i][j] -= fabsf((float)(qi - ki)) * lam;
                    }
                }
            }
            // online softmax (row groups = 16 lanes sharing ty)
#pragma unroll
            for (int i = 0; i < 4; i++) {
                float rm = fmaxf(fmaxf(s[i][0], s[i][1]), fmaxf(s[i][2], s[i][3]));
                rm = fmaxf(rm, __shfl_xor(rm, 1));
                rm = fmaxf(rm, __shfl_xor(rm, 2));
                rm = fmaxf(rm, __shfl_xor(rm, 4));
                rm = fmaxf(rm, __shfl_xor(rm, 8));
                float mn = fmaxf(m[i], rm);
                float sc = __expf(m[i] - mn);
                float rs = 0.f;
#pragma unroll
                for (int j = 0; j < 4; j++) {
                    s[i][j] = __expf(s[i][j] - mn);
                    rs += s[i][j];
                }
                rs += __shfl_xor(rs, 1); rs += __shfl_xor(rs, 2);
                rs += __shfl_xor(rs, 4); rs += __shfl_xor(rs, 8);
                lsum[i] = lsum[i] * sc + rs;
                m[i] = mn;
#pragma unroll
                for (int j = 0; j < 4; j++) acc[i][j] *= sc;
            }
            __syncthreads();  // all S-phase reads of KP done
            // write P transposed: KP[c][r]
#pragma unroll
            for (int j = 0; j < 4; j++) {
                float4 pv = {s[0][j], s[1][j], s[2][j], s[3][j]};
                *(float4*)&KP[tx * 4 + j][ty * 4] = pv;
            }
            __syncthreads();
            // O += P @ V : acc[i][j] += sum_c KP[c][4ty+i] * Vsh[c][4tx+j]
            for (int c = 0; c < 64; ++c) {
                float4 p4 = *(const float4*)&KP[c][ty * 4];
                float4 v4 = *(const float4*)&Vsh[c][tx * 4];
                float pa[4] = {p4.x, p4.y, p4.z, p4.w};
                float vb[4] = {v4.x, v4.y, v4.z, v4.w};
#pragma unroll
                for (int i = 0; i < 4; i++)
#pragma unroll
                    for (int j = 0; j < 4; j++)
                        acc[i][j] = fmaf(pa[i], vb[j], acc[i][j]);
            }
        }
#pragma unroll
        for (int i = 0; i < 4; i++) {
            float inv = 1.0f / lsum[i];
#pragma unroll
            for (int j = 0; j < 4; j++) {
                float o = acc[i][j] * inv;
                outS[i][j] = (branch == 0) ? o
                            : alpha * outS[i][j] + (1.f - alpha) * o;
            }
        }
    }
    // token-major write: out[(b*L + l)*H + h*64 + d]
#pragma unroll
    for (int i = 0; i < 4; i++) {
        int l = qt * 64 + ty * 4 + i;
        float4 v = {outS[i][0], outS[i][1], outS[i][2], outS[i][3]};
        *(float4*)&out[((size_t)(b * L_SEQ + l)) * HDIM + h * HD + tx * 4] = v;
    }
}

extern "C" void kernel_launch(void* const* d_in, const int* in_sizes, int n_in,
                              void* d_out, int out_size, void* d_ws, size_t ws_size,
                              hipStream_t stream) {
    const float* x      = (const float*)d_in[0];
    const float* Wq     = (const float*)d_in[1];
    const float* Wkvs   = (const float*)d_in[2];
    const float* Wkvl   = (const float*)d_in[3];
    const float* Wo     = (const float*)d_in[4];
    const float* mixw   = (const float*)d_in[5];
    const float* decayf = (const float*)d_in[6];
    float* out = (float*)d_out;

    const size_t T = (size_t)BATCH * L_SEQ * HDIM;  // 4M floats per tensor
    float* ws   = (float*)d_ws;
    float* q    = ws;
    float* ks   = q + T;
    float* vs   = ks + T;
    float* kl   = vs + T;
    float* vl   = kl + T;
    float* attn = vl + T;

    dim3 blk(256);
    gemm_k1024<<<dim3(16, 64), blk, 0, stream>>>(x, Wq, 1024, q, nullptr, 0);
    gemm_k1024<<<dim3(32, 64), blk, 0, stream>>>(x, Wkvs, 2048, ks, vs, 0);
    gemm_k1024<<<dim3(32, 64), blk, 0, stream>>>(x, Wkvl, 2048, kl, vl, 0);
    attn_kernel<<<dim3(16, 16, 4), blk, 0, stream>>>(q, ks, vs, kl, vl, mixw,
                                                     decayf, attn);
    gemm_k1024<<<dim3(16, 64), blk, 0, stream>>>(attn, Wo, 1024, out, nullptr, 1);
}

// Round 2
// 335.451 us; speedup vs baseline: 3.9474x; 3.9474x over previous
//
#include <hip/hip_runtime.h>
#include <math.h>
#include <stdint.h>

typedef unsigned short u16;
typedef __attribute__((ext_vector_type(8))) short bf16x8;
typedef __attribute__((ext_vector_type(4))) float f32x4;
typedef __attribute__((ext_vector_type(4))) unsigned short u16x4;

#define MFMA_BF16(A, B, C) __builtin_amdgcn_mfma_f32_16x16x32_bf16((A), (B), (C), 0, 0, 0)

__device__ __forceinline__ void async16(const void* g, const void* l) {
    __builtin_amdgcn_global_load_lds(
        (const __attribute__((address_space(1))) unsigned int*)(uintptr_t)g,
        (__attribute__((address_space(3))) unsigned int*)(uintptr_t)l, 16, 0, 0);
}

__device__ __forceinline__ u16 f2bf(float f) {
    unsigned u = __float_as_uint(f);
    u += 0x7fffu + ((u >> 16) & 1u);
    return (u16)(u >> 16);
}

// ---------------------------------------------------------------------------
// Converters
// ---------------------------------------------------------------------------
__global__ __launch_bounds__(256) void cvt_x(const float* __restrict__ x,
                                             u16* __restrict__ xb) {
    int i = blockIdx.x * 256 + threadIdx.x;
    float4 v = ((const float4*)x)[i];
    u16x4 o = {f2bf(v.x), f2bf(v.y), f2bf(v.z), f2bf(v.w)};
    ((u16x4*)xb)[i] = o;
}

// W fp32 [K=1024][N] -> Wt bf16 [N][1024]
__global__ __launch_bounds__(256) void cvt_w_t(const float* __restrict__ W,
                                               u16* __restrict__ Wt, int N) {
    __shared__ float tile[32][33];
    int kb = blockIdx.y * 32, nb = blockIdx.x * 32;
    int t = threadIdx.x;
    int r = t >> 3, c4 = (t & 7) * 4;
    float4 v = *(const float4*)&W[(size_t)(kb + r) * N + nb + c4];
    tile[r][c4] = v.x; tile[r][c4 + 1] = v.y;
    tile[r][c4 + 2] = v.z; tile[r][c4 + 3] = v.w;
    __syncthreads();
    u16x4 o = {f2bf(tile[c4 + 0][r]), f2bf(tile[c4 + 1][r]),
               f2bf(tile[c4 + 2][r]), f2bf(tile[c4 + 3][r])};
    *(u16x4*)&Wt[(size_t)(nb + r) * 1024 + kb + c4] = o;
}

// ---------------------------------------------------------------------------
// bf16 MFMA GEMM: C[M,N] = A[M,1024] * Bt[N,1024]^T  (m97 structure)
// 128x128 tile, BK=32, 4 waves (2x2), each wave 4x4 16x16 tiles.
// mode 0: dst0 = head-major bf16 [B,16,L,64]
// mode 1: cols<1024 -> dst0 head-major (K); cols>=1024 -> dst1 transposed
//         [B,16,64,L] (V)
// mode 2: dst0 = fp32 row-major [M,1024]
// ---------------------------------------------------------------------------
__global__ __launch_bounds__(256) void gemm_bf16(
    const u16* __restrict__ A, const u16* __restrict__ Bt, int mode,
    void* __restrict__ dst0, void* __restrict__ dst1)
{
    __shared__ u16 Alds[128][32];
    __shared__ u16 Blds[128][32];
    const int t = threadIdx.x;
    const int l = t & 63, w = t >> 6;
    const int wm = w & 1, wn = w >> 1;
    const int rowBase = blockIdx.y * 128, colBase = blockIdx.x * 128;
    const int lc = l & 15, lr4 = l >> 4;

    f32x4 acc[4][4];
#pragma unroll
    for (int i = 0; i < 4; i++)
#pragma unroll
        for (int j = 0; j < 4; j++) acc[i][j] = (f32x4){0.f, 0.f, 0.f, 0.f};

    const int srow = w * 32 + (l >> 2);   // staging row (first issue)
    const int sc8  = (l & 3) * 8;         // k-element offset within row
    const u16* Ag = A  + (size_t)(rowBase + srow) * 1024 + sc8;
    const u16* Bg = Bt + (size_t)(colBase + srow) * 1024 + sc8;

    for (int kt = 0; kt < 32; ++kt) {
        __syncthreads();
        const int ko = kt * 32;
        async16(Ag + ko,          &Alds[w * 32][0]);
        async16(Ag + ko + 16384,  &Alds[w * 32 + 16][0]);   // +16 rows * 1024
        async16(Bg + ko,          &Blds[w * 32][0]);
        async16(Bg + ko + 16384,  &Blds[w * 32 + 16][0]);
        __syncthreads();

        bf16x8 af[4], bf[4];
#pragma unroll
        for (int mt = 0; mt < 4; ++mt)
            af[mt] = *(const bf16x8*)&Alds[wm * 64 + mt * 16 + lc][lr4 * 8];
#pragma unroll
        for (int nt = 0; nt < 4; ++nt)
            bf[nt] = *(const bf16x8*)&Blds[wn * 64 + nt * 16 + lc][lr4 * 8];
#pragma unroll
        for (int mt = 0; mt < 4; ++mt)
#pragma unroll
            for (int nt = 0; nt < 4; ++nt)
                acc[mt][nt] = MFMA_BF16(af[mt], bf[nt], acc[mt][nt]);
    }

#pragma unroll
    for (int mt = 0; mt < 4; ++mt) {
#pragma unroll
        for (int nt = 0; nt < 4; ++nt) {
            const int gr0 = rowBase + wm * 64 + mt * 16 + lr4 * 4;
            const int gc0 = colBase + wn * 64 + nt * 16;
            if (mode == 2) {
                float* o = (float*)dst0;
#pragma unroll
                for (int r = 0; r < 4; ++r)
                    o[(size_t)(gr0 + r) * 1024 + gc0 + lc] = acc[mt][nt][r];
            } else {
                const int head = gc0 >> 6;
                if (mode == 0 || head < 16) {
                    u16* qd = (u16*)dst0;
#pragma unroll
                    for (int r = 0; r < 4; ++r) {
                        int gr = gr0 + r, b = gr >> 10, tok = gr & 1023;
                        qd[((size_t)(b * 16 + head) * 1024 + tok) * 64 +
                           ((gc0 & 63) + lc)] = f2bf(acc[mt][nt][r]);
                    }
                } else {
                    u16* vd = (u16*)dst1;
                    int b = gr0 >> 10, tok = gr0 & 1023;
                    int d = (gc0 & 63) + lc;
                    u16x4 pv = {f2bf(acc[mt][nt][0]), f2bf(acc[mt][nt][1]),
                                f2bf(acc[mt][nt][2]), f2bf(acc[mt][nt][3])};
                    *(u16x4*)&vd[((size_t)(b * 16 + head - 16) * 64 + d) * 1024 +
                                 tok] = pv;
                }
            }
        }
    }
}

// ---------------------------------------------------------------------------
// Flash attention, both branches, bf16 MFMA.
// Block = (64 q-rows, head, batch), 4 waves; wave w owns q-rows [w*16, +16).
// Q,K head-major [B,16,L,64]; V transposed [B,16,64,L]. Out bf16 [B,L,1024].
// ---------------------------------------------------------------------------
__global__ __launch_bounds__(256) void attn_mfma(
    const u16* __restrict__ Q, const u16* __restrict__ Ksb,
    const u16* __restrict__ Vsb, const u16* __restrict__ Klb,
    const u16* __restrict__ Vlb, const float* __restrict__ mixw,
    const float* __restrict__ decayf, u16* __restrict__ outb)
{
    __shared__ u16 Qs[2][64][32];   // [d-half][qrow][32 d]
    __shared__ u16 Kt[2][64][32];   // [d-half][krow][32 d]
    __shared__ u16 Vt[2][64][32];   // [k-half][d][32 krow]
    __shared__ u16 Ps[4][16][72];   // per wave: [qrow][krow(+pad)]

    const int t = threadIdx.x;
    const int l = t & 63, w = t >> 6;
    const int lc = l & 15, lr4 = l >> 4;
    const int qt = blockIdx.x, h = blockIdx.y, b = blockIdx.z;
    const size_t bh = (size_t)(b * 16 + h);
    const int qbase = qt * 64;

    const u16* Qg = Q + bh * (1024 * 64);
    const int srow = w * 16 + (l >> 2);   // staging row within 64-row tile
    const int sc8  = (l & 3) * 8;

    // stage Q once (2 halves)
    async16(Qg + (size_t)(qbase + srow) * 64 + 0  + sc8, &Qs[0][w * 16][0]);
    async16(Qg + (size_t)(qbase + srow) * 64 + 32 + sc8, &Qs[1][w * 16][0]);
    __syncthreads();   // drains vmcnt -> Q visible

    bf16x8 aQ[2];
    aQ[0] = *(const bf16x8*)&Qs[0][w * 16 + lc][lr4 * 8];
    aQ[1] = *(const bf16x8*)&Qs[1][w * 16 + lc][lr4 * 8];

    const float lam  = 1.0f - decayf[0];
    const float amix = 1.0f / (1.0f + __expf(-mixw[0]));

    float o0[4][4];   // normalized branch-0 output

    for (int branch = 0; branch < 2; ++branch) {
        const u16* Kg = (branch ? Klb : Ksb) + bh * (1024 * 64);
        const u16* Vg = (branch ? Vlb : Vsb) + bh * (64 * 1024);

        float mrun[4], lrun[4];
        f32x4 o[4];
#pragma unroll
        for (int r = 0; r < 4; ++r) { mrun[r] = -INFINITY; lrun[r] = 0.f; }
#pragma unroll
        for (int dt = 0; dt < 4; ++dt) o[dt] = (f32x4){0.f, 0.f, 0.f, 0.f};

        for (int kt = 0; kt < 16; ++kt) {
            __syncthreads();   // previous iter's readers done
            // K: rows = krow, halves over d
            async16(Kg + (size_t)(kt * 64 + srow) * 64 + 0  + sc8, &Kt[0][w * 16][0]);
            async16(Kg + (size_t)(kt * 64 + srow) * 64 + 32 + sc8, &Kt[1][w * 16][0]);
            // V: rows = d, halves over krow
            async16(Vg + (size_t)srow * 1024 + kt * 64 + 0  + sc8, &Vt[0][w * 16][0]);
            async16(Vg + (size_t)srow * 1024 + kt * 64 + 32 + sc8, &Vt[1][w * 16][0]);
            __syncthreads();   // vmcnt drained -> tiles visible

            // S = Q K^T  (C-layout: row=qrow_local lr4*4+r, col=krow nt*16+lc)
            f32x4 s[4];
#pragma unroll
            for (int nt = 0; nt < 4; ++nt) {
                s[nt] = (f32x4){0.f, 0.f, 0.f, 0.f};
                bf16x8 b0 = *(const bf16x8*)&Kt[0][nt * 16 + lc][lr4 * 8];
                bf16x8 b1 = *(const bf16x8*)&Kt[1][nt * 16 + lc][lr4 * 8];
                s[nt] = MFMA_BF16(aQ[0], b0, s[nt]);
                s[nt] = MFMA_BF16(aQ[1], b1, s[nt]);
            }

            float sv[4][4];
#pragma unroll
            for (int nt = 0; nt < 4; ++nt)
#pragma unroll
                for (int r = 0; r < 4; ++r) {
                    float x = s[nt][r] * 0.125f;
                    if (branch == 0) {
                        int qg = qbase + w * 16 + lr4 * 4 + r;
                        int kg = kt * 64 + nt * 16 + lc;
                        x -= fabsf((float)(qg - kg)) * lam;
                    }
                    sv[nt][r] = x;
                }

            float pf[4][4], sc[4];
#pragma unroll
            for (int r = 0; r < 4; ++r) {
                float mx = fmaxf(fmaxf(sv[0][r], sv[1][r]),
                                 fmaxf(sv[2][r], sv[3][r]));
                mx = fmaxf(mx, __shfl_xor(mx, 1));
                mx = fmaxf(mx, __shfl_xor(mx, 2));
                mx = fmaxf(mx, __shfl_xor(mx, 4));
                mx = fmaxf(mx, __shfl_xor(mx, 8));
                float mn = fmaxf(mrun[r], mx);
                sc[r] = __expf(mrun[r] - mn);
                mrun[r] = mn;
                float rs = 0.f;
#pragma unroll
                for (int nt = 0; nt < 4; ++nt) {
                    pf[nt][r] = __expf(sv[nt][r] - mn);
                    rs += pf[nt][r];
                }
                rs += __shfl_xor(rs, 1); rs += __shfl_xor(rs, 2);
                rs += __shfl_xor(rs, 4); rs += __shfl_xor(rs, 8);
                lrun[r] = lrun[r] * sc[r] + rs;
            }
#pragma unroll
            for (int dt = 0; dt < 4; ++dt)
#pragma unroll
                for (int r = 0; r < 4; ++r) o[dt][r] *= sc[r];

            // P -> LDS (A-operand layout), per-wave private region
#pragma unroll
            for (int nt = 0; nt < 4; ++nt)
#pragma unroll
                for (int r = 0; r < 4; ++r)
                    Ps[w][lr4 * 4 + r][nt * 16 + lc] = f2bf(pf[nt][r]);

            bf16x8 pa0 = *(const bf16x8*)&Ps[w][lc][lr4 * 8];
            bf16x8 pa1 = *(const bf16x8*)&Ps[w][lc][32 + lr4 * 8];
#pragma unroll
            for (int dt = 0; dt < 4; ++dt) {
                bf16x8 v0 = *(const bf16x8*)&Vt[0][dt * 16 + lc][lr4 * 8];
                bf16x8 v1 = *(const bf16x8*)&Vt[1][dt * 16 + lc][lr4 * 8];
                o[dt] = MFMA_BF16(pa0, v0, o[dt]);
                o[dt] = MFMA_BF16(pa1, v1, o[dt]);
            }
        }

        if (branch == 0) {
#pragma unroll
            for (int r = 0; r < 4; ++r) {
                float inv = 1.0f / lrun[r];
#pragma unroll
                for (int dt = 0; dt < 4; ++dt) o0[dt][r] = o[dt][r] * inv;
            }
        } else {
#pragma unroll
            for (int r = 0; r < 4; ++r) {
                float inv = 1.0f / lrun[r];
                int qg = qbase + w * 16 + lr4 * 4 + r;
#pragma unroll
                for (int dt = 0; dt < 4; ++dt) {
                    float val = amix * o0[dt][r] +
                                (1.f - amix) * o[dt][r] * inv;
                    outb[((size_t)(b * 1024 + qg)) * 1024 + h * 64 + dt * 16 + lc] =
                        f2bf(val);
                }
            }
        }
    }
}

// ---------------------------------------------------------------------------
extern "C" void kernel_launch(void* const* d_in, const int* in_sizes, int n_in,
                              void* d_out, int out_size, void* d_ws, size_t ws_size,
                              hipStream_t stream) {
    const float* x      = (const float*)d_in[0];
    const float* Wq     = (const float*)d_in[1];
    const float* Wkvs   = (const float*)d_in[2];
    const float* Wkvl   = (const float*)d_in[3];
    const float* Wo     = (const float*)d_in[4];
    const float* mixw   = (const float*)d_in[5];
    const float* decayf = (const float*)d_in[6];

    const size_t M1 = 1024 * 1024;
    u16* ws    = (u16*)d_ws;
    u16* xb    = ws;               // 4M
    u16* wqt   = xb + 4 * M1;      // 1M
    u16* wkvst = wqt + 1 * M1;     // 2M
    u16* wkvlt = wkvst + 2 * M1;   // 2M
    u16* wot   = wkvlt + 2 * M1;   // 1M
    u16* qb    = wot + 1 * M1;     // 4M
    u16* ksb   = qb + 4 * M1;      // 4M
    u16* vsb   = ksb + 4 * M1;     // 4M  (transposed [B,16,64,L])
    u16* klb   = vsb + 4 * M1;     // 4M
    u16* vlb   = klb + 4 * M1;     // 4M
    u16* attnb = vlb + 4 * M1;     // 4M

    cvt_x<<<4096, 256, 0, stream>>>(x, xb);
    cvt_w_t<<<dim3(32, 32), 256, 0, stream>>>(Wq, wqt, 1024);
    cvt_w_t<<<dim3(64, 32), 256, 0, stream>>>(Wkvs, wkvst, 2048);
    cvt_w_t<<<dim3(64, 32), 256, 0, stream>>>(Wkvl, wkvlt, 2048);
    cvt_w_t<<<dim3(32, 32), 256, 0, stream>>>(Wo, wot, 1024);

    gemm_bf16<<<dim3(8, 32), 256, 0, stream>>>(xb, wqt, 0, qb, nullptr);
    gemm_bf16<<<dim3(16, 32), 256, 0, stream>>>(xb, wkvst, 1, ksb, vsb);
    gemm_bf16<<<dim3(16, 32), 256, 0, stream>>>(xb, wkvlt, 1, klb, vlb);

    attn_mfma<<<dim3(16, 16, 4), 256, 0, stream>>>(qb, ksb, vsb, klb, vlb,
                                                   mixw, decayf, attnb);

    gemm_bf16<<<dim3(8, 32), 256, 0, stream>>>(attnb, wot, 2, (void*)d_out,
                                               nullptr);
}

// Round 3
// 261.858 us; speedup vs baseline: 5.0568x; 1.2810x over previous
//
#include <hip/hip_runtime.h>
#include <hip/hip_bf16.h>
#include <math.h>
#include <stdint.h>

typedef unsigned short u16;
typedef __attribute__((ext_vector_type(8))) short bf16x8;
typedef __attribute__((ext_vector_type(4))) float f32x4;
typedef __attribute__((ext_vector_type(4))) unsigned short u16x4;

#define MFMA_BF16(A, B, C) __builtin_amdgcn_mfma_f32_16x16x32_bf16((A), (B), (C), 0, 0, 0)

__device__ __forceinline__ void async16(const void* g, const void* l) {
    __builtin_amdgcn_global_load_lds(
        (const __attribute__((address_space(1))) unsigned int*)(uintptr_t)g,
        (__attribute__((address_space(3))) unsigned int*)(uintptr_t)l, 16, 0, 0);
}

__device__ __forceinline__ u16 f2bf(float f) {
    unsigned u = __float_as_uint(f);
    u += 0x7fffu + ((u >> 16) & 1u);
    return (u16)(u >> 16);
}

__device__ __forceinline__ unsigned pack2(float a, float b) {
    __hip_bfloat162 h = __float22bfloat162_rn(float2{a, b});
    return *reinterpret_cast<unsigned*>(&h);
}

// ---------------------------------------------------------------------------
// Converters
// ---------------------------------------------------------------------------
__global__ __launch_bounds__(256) void cvt_x(const float* __restrict__ x,
                                             u16* __restrict__ xb) {
    int i = blockIdx.x * 256 + threadIdx.x;
    float4 v = ((const float4*)x)[i];
    u16x4 o = {f2bf(v.x), f2bf(v.y), f2bf(v.z), f2bf(v.w)};
    ((u16x4*)xb)[i] = o;
}

// All 4 weights fp32 [K=1024][N] -> bf16 [N][1024] in one launch.
__global__ __launch_bounds__(256) void cvt_w_all(
    const float* __restrict__ Wq, const float* __restrict__ Wks,
    const float* __restrict__ Wkl, const float* __restrict__ Wo,
    u16* __restrict__ wqt, u16* __restrict__ wkst,
    u16* __restrict__ wklt, u16* __restrict__ wot)
{
    __shared__ float tile[32][33];
    int x = blockIdx.x;
    const float* W; u16* Wt; int N, nb;
    if (x < 32)       { W = Wq;  Wt = wqt;  N = 1024; nb = x * 32; }
    else if (x < 96)  { W = Wks; Wt = wkst; N = 2048; nb = (x - 32) * 32; }
    else if (x < 160) { W = Wkl; Wt = wklt; N = 2048; nb = (x - 96) * 32; }
    else              { W = Wo;  Wt = wot;  N = 1024; nb = (x - 160) * 32; }
    int kb = blockIdx.y * 32;
    int t = threadIdx.x;
    int r = t >> 3, c4 = (t & 7) * 4;
    float4 v = *(const float4*)&W[(size_t)(kb + r) * N + nb + c4];
    tile[r][c4] = v.x; tile[r][c4 + 1] = v.y;
    tile[r][c4 + 2] = v.z; tile[r][c4 + 3] = v.w;
    __syncthreads();
    u16x4 o = {f2bf(tile[c4 + 0][r]), f2bf(tile[c4 + 1][r]),
               f2bf(tile[c4 + 2][r]), f2bf(tile[c4 + 3][r])};
    *(u16x4*)&Wt[(size_t)(nb + r) * 1024 + kb + c4] = o;
}

// ---------------------------------------------------------------------------
// Fused projection GEMM: [4096,1024] x {Wq, Wkv_s, Wkv_l} in one launch.
// 128x128 tile, BK=32, 4 waves, m97-style global_load_lds staging.
// Q/K epilogue: head-major [B,16,L,64]; V epilogue: transposed [B,16,64,L].
// ---------------------------------------------------------------------------
__global__ __launch_bounds__(256) void gemm_proj(
    const u16* __restrict__ A, const u16* __restrict__ wq,
    const u16* __restrict__ wks, const u16* __restrict__ wkl,
    u16* __restrict__ qd, u16* __restrict__ ksd, u16* __restrict__ vsd,
    u16* __restrict__ kld, u16* __restrict__ vld)
{
    __shared__ u16 Alds[128][32];
    __shared__ u16 Blds[128][32];
    const int cx = blockIdx.x;
    const u16* Bt; u16* d0; u16* d1; int colBase;
    if (cx < 8)       { Bt = wq;  colBase = cx * 128;        d0 = qd;  d1 = nullptr; }
    else if (cx < 24) { Bt = wks; colBase = (cx - 8) * 128;  d0 = ksd; d1 = vsd; }
    else              { Bt = wkl; colBase = (cx - 24) * 128; d0 = kld; d1 = vld; }

    const int t = threadIdx.x;
    const int l = t & 63, w = t >> 6;
    const int wm = w & 1, wn = w >> 1;
    const int rowBase = blockIdx.y * 128;
    const int lc = l & 15, lr4 = l >> 4;

    f32x4 acc[4][4];
#pragma unroll
    for (int i = 0; i < 4; i++)
#pragma unroll
        for (int j = 0; j < 4; j++) acc[i][j] = (f32x4){0.f, 0.f, 0.f, 0.f};

    const int srow = w * 32 + (l >> 2);
    const int sc8  = (l & 3) * 8;
    const u16* Ag = A  + (size_t)(rowBase + srow) * 1024 + sc8;
    const u16* Bg = Bt + (size_t)(colBase + srow) * 1024 + sc8;

    for (int kt = 0; kt < 32; ++kt) {
        __syncthreads();
        const int ko = kt * 32;
        async16(Ag + ko,         &Alds[w * 32][0]);
        async16(Ag + ko + 16384, &Alds[w * 32 + 16][0]);
        async16(Bg + ko,         &Blds[w * 32][0]);
        async16(Bg + ko + 16384, &Blds[w * 32 + 16][0]);
        __syncthreads();

        bf16x8 af[4], bf[4];
#pragma unroll
        for (int mt = 0; mt < 4; ++mt)
            af[mt] = *(const bf16x8*)&Alds[wm * 64 + mt * 16 + lc][lr4 * 8];
#pragma unroll
        for (int nt = 0; nt < 4; ++nt)
            bf[nt] = *(const bf16x8*)&Blds[wn * 64 + nt * 16 + lc][lr4 * 8];
#pragma unroll
        for (int mt = 0; mt < 4; ++mt)
#pragma unroll
            for (int nt = 0; nt < 4; ++nt)
                acc[mt][nt] = MFMA_BF16(af[mt], bf[nt], acc[mt][nt]);
    }

#pragma unroll
    for (int mt = 0; mt < 4; ++mt) {
#pragma unroll
        for (int nt = 0; nt < 4; ++nt) {
            const int gr0 = rowBase + wm * 64 + mt * 16 + lr4 * 4;
            const int gc0 = colBase + wn * 64 + nt * 16;
            const int head = gc0 >> 6;
            if (head < 16) {   // Q or K: head-major [B,16,L,64]
#pragma unroll
                for (int r = 0; r < 4; ++r) {
                    int gr = gr0 + r, b = gr >> 10, tok = gr & 1023;
                    d0[((size_t)(b * 16 + head) * 1024 + tok) * 64 +
                       ((gc0 & 63) + lc)] = f2bf(acc[mt][nt][r]);
                }
            } else {           // V: transposed [B,16,64,L]
                int b = gr0 >> 10, tok = gr0 & 1023;
                int d = (gc0 & 63) + lc;
                u16x4 pv = {f2bf(acc[mt][nt][0]), f2bf(acc[mt][nt][1]),
                            f2bf(acc[mt][nt][2]), f2bf(acc[mt][nt][3])};
                *(u16x4*)&d1[((size_t)(b * 16 + head - 16) * 64 + d) * 1024 +
                             tok] = pv;
            }
        }
    }
}

// ---------------------------------------------------------------------------
// Output GEMM: C[4096,1024] fp32 = attn_bf16 [4096,1024] x Wo^T[1024,1024]
// ---------------------------------------------------------------------------
__global__ __launch_bounds__(256) void gemm_out(
    const u16* __restrict__ A, const u16* __restrict__ Bt,
    float* __restrict__ dst)
{
    __shared__ u16 Alds[128][32];
    __shared__ u16 Blds[128][32];
    const int t = threadIdx.x;
    const int l = t & 63, w = t >> 6;
    const int wm = w & 1, wn = w >> 1;
    const int rowBase = blockIdx.y * 128, colBase = blockIdx.x * 128;
    const int lc = l & 15, lr4 = l >> 4;

    f32x4 acc[4][4];
#pragma unroll
    for (int i = 0; i < 4; i++)
#pragma unroll
        for (int j = 0; j < 4; j++) acc[i][j] = (f32x4){0.f, 0.f, 0.f, 0.f};

    const int srow = w * 32 + (l >> 2);
    const int sc8  = (l & 3) * 8;
    const u16* Ag = A  + (size_t)(rowBase + srow) * 1024 + sc8;
    const u16* Bg = Bt + (size_t)(colBase + srow) * 1024 + sc8;

    for (int kt = 0; kt < 32; ++kt) {
        __syncthreads();
        const int ko = kt * 32;
        async16(Ag + ko,         &Alds[w * 32][0]);
        async16(Ag + ko + 16384, &Alds[w * 32 + 16][0]);
        async16(Bg + ko,         &Blds[w * 32][0]);
        async16(Bg + ko + 16384, &Blds[w * 32 + 16][0]);
        __syncthreads();

        bf16x8 af[4], bf[4];
#pragma unroll
        for (int mt = 0; mt < 4; ++mt)
            af[mt] = *(const bf16x8*)&Alds[wm * 64 + mt * 16 + lc][lr4 * 8];
#pragma unroll
        for (int nt = 0; nt < 4; ++nt)
            bf[nt] = *(const bf16x8*)&Blds[wn * 64 + nt * 16 + lc][lr4 * 8];
#pragma unroll
        for (int mt = 0; mt < 4; ++mt)
#pragma unroll
            for (int nt = 0; nt < 4; ++nt)
                acc[mt][nt] = MFMA_BF16(af[mt], bf[nt], acc[mt][nt]);
    }

#pragma unroll
    for (int mt = 0; mt < 4; ++mt)
#pragma unroll
        for (int nt = 0; nt < 4; ++nt) {
            const int gr0 = rowBase + wm * 64 + mt * 16 + lr4 * 4;
            const int gc0 = colBase + wn * 64 + nt * 16;
#pragma unroll
            for (int r = 0; r < 4; ++r)
                dst[(size_t)(gr0 + r) * 1024 + gc0 + lc] = acc[mt][nt][r];
        }
}

// ---------------------------------------------------------------------------
// Flash attention, transposed-MFMA formulation (S^T, O^T).
// Block = 128 q-rows x head x batch; 4 waves x 32 q-rows.
// Per k-tile (64 rows):  S^T = K Q^T  (A=K, B=Q^T);  O^T += V^T P^T.
// Fixed-max softmax (scores bounded), per-lane partial sums, no in-loop
// shuffles, packed b64 P writes, b128 P/B reads.
// ---------------------------------------------------------------------------
__global__ __launch_bounds__(256, 2) void attn_mfma(
    const u16* __restrict__ Q, const u16* __restrict__ Ksb,
    const u16* __restrict__ Vsb, const u16* __restrict__ Klb,
    const u16* __restrict__ Vlb, const float* __restrict__ mixw,
    const float* __restrict__ decayf, u16* __restrict__ outb)
{
    __shared__ u16 Kt[2][64][32];             // [d-half][krow][32 d]
    __shared__ u16 Vt[2][64][32];             // [krow-half][d][32 krow]
    __shared__ union {
        u16 q[2][128][32];                    // [d-half][qrow][32 d]
        u16 p[4][32][72];                     // per wave [qrow][krow(+8 pad)]
    } QP;

    const int t = threadIdx.x;
    const int l = t & 63, w = t >> 6;
    const int lc = l & 15, lr4 = l >> 4;
    const int qt = blockIdx.x, h = blockIdx.y, b = blockIdx.z;
    const size_t bh = (size_t)(b * 16 + h);
    const int qbase = qt * 128;
    const u16* Qg = Q + bh * (1024 * 64);

    // ---- stage Q (128 rows x 64 d) once: 16 async16, 4 per wave ----
#pragma unroll
    for (int i = 0; i < 4; i++) {
        int id = w * 4 + i, kh = id >> 3, ch = id & 7;
        async16(Qg + (size_t)(qbase + ch * 16 + (l >> 2)) * 64 + kh * 32 +
                    (l & 3) * 8,
                &QP.q[kh][ch * 16][0]);
    }
    __syncthreads();
    bf16x8 aQ[2][2];   // [qgroup][d-half] B-operand frags
#pragma unroll
    for (int qg = 0; qg < 2; ++qg)
#pragma unroll
        for (int kh = 0; kh < 2; ++kh)
            aQ[qg][kh] =
                *(const bf16x8*)&QP.q[kh][w * 32 + qg * 16 + lc][lr4 * 8];
    // (loop's first barrier protects QP.q before P writes reuse it)

    const float C1   = 0.125f * 1.44269504f;
    const float C2   = (1.0f - decayf[0]) * 1.44269504f;
    const float amix = 1.0f / (1.0f + __expf(-mixw[0]));
    const float qf   = (float)(qbase + w * 32 + lc);

    f32x4 o0[2][4];

    for (int branch = 0; branch < 2; ++branch) {
        const u16* Kg = (branch ? Klb : Ksb) + bh * (1024 * 64);
        const u16* Vg = (branch ? Vlb : Vsb) + bh * (64 * 1024);

        float lrun[2] = {0.f, 0.f};
        f32x4 o[2][4];
#pragma unroll
        for (int qg = 0; qg < 2; ++qg)
#pragma unroll
            for (int dt = 0; dt < 4; ++dt) o[qg][dt] = (f32x4){0.f, 0.f, 0.f, 0.f};

        for (int kt = 0; kt < 16; ++kt) {
            __syncthreads();
            // stage K (krow-major, 2 d-halves) + V^T (d-major, 2 krow-halves)
#pragma unroll
            for (int i = 0; i < 4; i++) {
                int id = w * 4 + i;
                int kh = (id >> 2) & 1, ch = id & 3;
                if (id < 8)
                    async16(Kg + (size_t)(kt * 64 + ch * 16 + (l >> 2)) * 64 +
                                kh * 32 + (l & 3) * 8,
                            &Kt[kh][ch * 16][0]);
                else
                    async16(Vg + (size_t)(ch * 16 + (l >> 2)) * 1024 + kt * 64 +
                                kh * 32 + (l & 3) * 8,
                            &Vt[kh][ch * 16][0]);
            }
            __syncthreads();

            // K A-frags (shared across both q-groups)
            bf16x8 ak[4][2];
#pragma unroll
            for (int nt = 0; nt < 4; ++nt) {
                ak[nt][0] = *(const bf16x8*)&Kt[0][nt * 16 + lc][lr4 * 8];
                ak[nt][1] = *(const bf16x8*)&Kt[1][nt * 16 + lc][lr4 * 8];
            }

#pragma unroll
            for (int qg = 0; qg < 2; ++qg) {
                f32x4 s[4];
#pragma unroll
                for (int nt = 0; nt < 4; ++nt) {
                    s[nt] = (f32x4){0.f, 0.f, 0.f, 0.f};
                    s[nt] = MFMA_BF16(ak[nt][0], aQ[qg][0], s[nt]);
                    s[nt] = MFMA_BF16(ak[nt][1], aQ[qg][1], s[nt]);
                }
                // softmax (fixed max) + pack P
                const float d0 = qf + (float)(qg * 16 - kt * 64 - lr4 * 4);
                float sum = 0.f;
#pragma unroll
                for (int nt = 0; nt < 4; ++nt) {
                    float p[4];
#pragma unroll
                    for (int r = 0; r < 4; ++r) {
                        float a = s[nt][r] * C1;
                        if (branch == 0)
                            a -= fabsf(d0 - (float)(nt * 16 + r)) * C2;
                        p[r] = exp2f(a);
                        sum += p[r];
                    }
                    uint2 w2 = {pack2(p[0], p[1]), pack2(p[2], p[3])};
                    *(uint2*)&QP.p[w][qg * 16 + lc][nt * 16 + lr4 * 4] = w2;
                }
                lrun[qg] += sum;
            }

            // O^T += V^T P^T
            bf16x8 pb[2][2];
#pragma unroll
            for (int qg = 0; qg < 2; ++qg)
#pragma unroll
                for (int c = 0; c < 2; ++c)
                    pb[qg][c] = *(const bf16x8*)&QP.p[w][qg * 16 + lc]
                                                     [c * 32 + lr4 * 8];
#pragma unroll
            for (int dt = 0; dt < 4; ++dt) {
                bf16x8 v0 = *(const bf16x8*)&Vt[0][dt * 16 + lc][lr4 * 8];
                bf16x8 v1 = *(const bf16x8*)&Vt[1][dt * 16 + lc][lr4 * 8];
#pragma unroll
                for (int qg = 0; qg < 2; ++qg) {
                    o[qg][dt] = MFMA_BF16(v0, pb[qg][0], o[qg][dt]);
                    o[qg][dt] = MFMA_BF16(v1, pb[qg][1], o[qg][dt]);
                }
            }
        }

        // deferred cross-quad reduction of the softmax denominator
        float inv[2];
#pragma unroll
        for (int qg = 0; qg < 2; ++qg) {
            float s = lrun[qg];
            s += __shfl_xor(s, 16);
            s += __shfl_xor(s, 32);
            inv[qg] = 1.0f / s;
        }

        if (branch == 0) {
#pragma unroll
            for (int qg = 0; qg < 2; ++qg)
#pragma unroll
                for (int dt = 0; dt < 4; ++dt)
#pragma unroll
                    for (int r = 0; r < 4; ++r)
                        o0[qg][dt][r] = o[qg][dt][r] * inv[qg];
        } else {
#pragma unroll
            for (int qg = 0; qg < 2; ++qg) {
                int qrow = qbase + w * 32 + qg * 16 + lc;
                u16* op = outb + ((size_t)(b * 1024) + qrow) * 1024 + h * 64;
#pragma unroll
                for (int dt = 0; dt < 4; ++dt) {
                    float v[4];
#pragma unroll
                    for (int r = 0; r < 4; ++r)
                        v[r] = amix * o0[qg][dt][r] +
                               (1.f - amix) * o[qg][dt][r] * inv[qg];
                    uint2 w2 = {pack2(v[0], v[1]), pack2(v[2], v[3])};
                    *(uint2*)&op[dt * 16 + lr4 * 4] = w2;
                }
            }
        }
    }
}

// ---------------------------------------------------------------------------
extern "C" void kernel_launch(void* const* d_in, const int* in_sizes, int n_in,
                              void* d_out, int out_size, void* d_ws, size_t ws_size,
                              hipStream_t stream) {
    const float* x      = (const float*)d_in[0];
    const float* Wq     = (const float*)d_in[1];
    const float* Wkvs   = (const float*)d_in[2];
    const float* Wkvl   = (const float*)d_in[3];
    const float* Wo     = (const float*)d_in[4];
    const float* mixw   = (const float*)d_in[5];
    const float* decayf = (const float*)d_in[6];

    const size_t M1 = 1024 * 1024;
    u16* ws    = (u16*)d_ws;
    u16* xb    = ws;               // 4M
    u16* wqt   = xb + 4 * M1;      // 1M
    u16* wkvst = wqt + 1 * M1;     // 2M
    u16* wkvlt = wkvst + 2 * M1;   // 2M
    u16* wot   = wkvlt + 2 * M1;   // 1M
    u16* qb    = wot + 1 * M1;     // 4M
    u16* ksb   = qb + 4 * M1;      // 4M
    u16* vsb   = ksb + 4 * M1;     // 4M  ([B,16,64,L])
    u16* klb   = vsb + 4 * M1;     // 4M
    u16* vlb   = klb + 4 * M1;     // 4M
    u16* attnb = vlb + 4 * M1;     // 4M

    cvt_x<<<4096, 256, 0, stream>>>(x, xb);
    cvt_w_all<<<dim3(192, 32), 256, 0, stream>>>(Wq, Wkvs, Wkvl, Wo,
                                                 wqt, wkvst, wkvlt, wot);
    gemm_proj<<<dim3(40, 32), 256, 0, stream>>>(xb, wqt, wkvst, wkvlt,
                                                qb, ksb, vsb, klb, vlb);
    attn_mfma<<<dim3(8, 16, 4), 256, 0, stream>>>(qb, ksb, vsb, klb, vlb,
                                                  mixw, decayf, attnb);
    gemm_out<<<dim3(8, 32), 256, 0, stream>>>(attnb, wot, (float*)d_out);
}